// Round 11
// baseline (524.046 us; speedup 1.0000x reference)
//
#include <hip/hip_runtime.h>
#include <math.h>

#define D 128
#define WS_PAD 132  // 128+4: breaks stride-128 bank pattern, keeps 16B align

typedef short bf16x8 __attribute__((ext_vector_type(8)));  // 8 bf16 in 4 VGPRs
typedef float f32x4 __attribute__((ext_vector_type(4)));

__device__ __forceinline__ unsigned short f2bf(float f) {
  unsigned u = __float_as_uint(f);
  u += 0x7FFFu + ((u >> 16) & 1u);  // round-to-nearest-even
  return (unsigned short)(u >> 16);
}

__device__ __forceinline__ float bf2f(unsigned short h) {
  return __uint_as_float(((unsigned)h) << 16);
}

__device__ __forceinline__ float bflo(unsigned u) { return __uint_as_float(u << 16); }
__device__ __forceinline__ float bfhi(unsigned u) { return __uint_as_float(u & 0xFFFF0000u); }

// ---------------- weight-table prep (16 blocks, runs before count||GEMM1) ----------------

__global__ __launch_bounds__(256) void wprep_kernel(const float* __restrict__ W2,
                                                    unsigned short* __restrict__ W2bf,
                                                    const float* __restrict__ W1,
                                                    unsigned short* __restrict__ W1h,
                                                    unsigned short* __restrict__ W1l) {
  int which = blockIdx.x;  // 0..15
  if (which < 8) {
    int t = which * 256 + threadIdx.x;  // 0..2047
    #pragma unroll
    for (int q = 0; q < 2; ++q) {
      int idx = t + q * 2048;  // float4 index, 0..4095
      float4 w = ((const float4*)W2)[idx];
      ushort4 o;
      o.x = f2bf(w.x); o.y = f2bf(w.y); o.z = f2bf(w.z); o.w = f2bf(w.w);
      ((ushort4*)W2bf)[idx] = o;
    }
  } else {
    int t = (which - 8) * 256 + threadIdx.x;
    #pragma unroll
    for (int q = 0; q < 2; ++q) {
      int idx = t + q * 2048;
      float4 w = ((const float4*)W1)[idx];
      ushort4 hi, lo;
      hi.x = f2bf(w.x); lo.x = f2bf(w.x - bf2f(hi.x));
      hi.y = f2bf(w.y); lo.y = f2bf(w.y - bf2f(hi.y));
      hi.z = f2bf(w.z); lo.z = f2bf(w.z - bf2f(hi.z));
      hi.w = f2bf(w.w); lo.w = f2bf(w.w - bf2f(hi.w));
      ((ushort4*)W1h)[idx] = hi;
      ((ushort4*)W1l)[idx] = lo;
    }
  }
}

// ---------------- fused: degree count + rank (atomic-bound) || GEMM1_raw (MFMA) ----------------

#define FUSED_GRID 2048
#define G1_PITCH 136

__global__ __launch_bounds__(256) void count_gemm1_kernel(
    const int* __restrict__ dst, int E, int* __restrict__ deg, int* __restrict__ rank,
    const float* __restrict__ X,
    const unsigned short* __restrict__ W1h, const unsigned short* __restrict__ W1l,
    unsigned short* __restrict__ H, int n) {
  __shared__ unsigned short Ths[32 * G1_PITCH];  // 8.7 KB
  __shared__ unsigned short Tls[32 * G1_PITCH];  // 8.7 KB
  int sub = blockIdx.x & 7;
  if (sub < 4) {
    // count + rank: 1024 blocks, 4 edges/thread, grid-strided
    int cb = (blockIdx.x >> 3) * 4 + sub;
    const int T4 = 1024 * 256 * 4;
    int t = cb * 256 + threadIdx.x;
    const bool al16 = ((E & 3) == 0);
    for (int e0 = t * 4; e0 < E; e0 += T4) {
      if (e0 + 4 <= E && al16) {
        int4 d = *(const int4*)(dst + e0);
        int r0 = atomicAdd(&deg[d.x], 1);
        int r1 = atomicAdd(&deg[d.y], 1);
        int r2 = atomicAdd(&deg[d.z], 1);
        int r3 = atomicAdd(&deg[d.w], 1);
        *(int4*)(rank + e0) = make_int4(r0, r1, r2, r3);
      } else {
        for (int e = e0; e < E && e < e0 + 4; ++e) rank[e] = atomicAdd(&deg[dst[e]], 1);
      }
    }
  } else {
    // GEMM1_raw: 1024 blocks, 32 rows per tile, grid-strided; bf16x3 fp32-accurate
    int gb = (blockIdx.x >> 3) * 4 + (sub - 4);
    const int tid = threadIdx.x;
    const int wv = tid >> 6;       // 0..3
    const int lane = tid & 63;
    const int m = lane & 15;
    const int quad = lane >> 4;    // 0..3
    const int mt = wv >> 1;        // 0..1  (16-row m-tile)
    const int ntb = (wv & 1) * 4;  // n-tile base: 4 consecutive 16-col tiles
    const int ntiles = (n + 31) >> 5;

    for (int tile = gb; tile < ntiles; tile += 1024) {
      const int row0 = tile << 5;
      const int rows_here = min(32, n - row0);
      __syncthreads();  // protect LDS from previous iteration's readers
      {
        const float4* Xg = (const float4*)(X + (size_t)row0 * D);
        int tmax = rows_here * 32;
        for (int t = tid; t < tmax; t += 256) {
          float4 xv = Xg[t];
          int r = t >> 5, c4 = (t & 31) << 2;
          ushort4 hi, lo;
          hi.x = f2bf(xv.x); lo.x = f2bf(xv.x - bf2f(hi.x));
          hi.y = f2bf(xv.y); lo.y = f2bf(xv.y - bf2f(hi.y));
          hi.z = f2bf(xv.z); lo.z = f2bf(xv.z - bf2f(hi.z));
          hi.w = f2bf(xv.w); lo.w = f2bf(xv.w - bf2f(hi.w));
          *(ushort4*)&Ths[r * G1_PITCH + c4] = hi;
          *(ushort4*)&Tls[r * G1_PITCH + c4] = lo;
        }
      }
      __syncthreads();

      f32x4 acc0 = {0.f, 0.f, 0.f, 0.f};
      f32x4 acc1 = {0.f, 0.f, 0.f, 0.f};
      f32x4 acc2 = {0.f, 0.f, 0.f, 0.f};
      f32x4 acc3 = {0.f, 0.f, 0.f, 0.f};
      #pragma unroll
      for (int s = 0; s < 4; ++s) {
        int k = (s << 5) + (quad << 3);
        bf16x8 ah = *(const bf16x8*)&Ths[(mt * 16 + m) * G1_PITCH + k];
        bf16x8 al = *(const bf16x8*)&Tls[(mt * 16 + m) * G1_PITCH + k];
        bf16x8 bh0 = *(const bf16x8*)&W1h[(size_t)((ntb + 0) * 16 + m) * 128 + k];
        bf16x8 bl0 = *(const bf16x8*)&W1l[(size_t)((ntb + 0) * 16 + m) * 128 + k];
        acc0 = __builtin_amdgcn_mfma_f32_16x16x32_bf16(ah, bh0, acc0, 0, 0, 0);
        acc0 = __builtin_amdgcn_mfma_f32_16x16x32_bf16(al, bh0, acc0, 0, 0, 0);
        acc0 = __builtin_amdgcn_mfma_f32_16x16x32_bf16(ah, bl0, acc0, 0, 0, 0);
        bf16x8 bh1 = *(const bf16x8*)&W1h[(size_t)((ntb + 1) * 16 + m) * 128 + k];
        bf16x8 bl1 = *(const bf16x8*)&W1l[(size_t)((ntb + 1) * 16 + m) * 128 + k];
        acc1 = __builtin_amdgcn_mfma_f32_16x16x32_bf16(ah, bh1, acc1, 0, 0, 0);
        acc1 = __builtin_amdgcn_mfma_f32_16x16x32_bf16(al, bh1, acc1, 0, 0, 0);
        acc1 = __builtin_amdgcn_mfma_f32_16x16x32_bf16(ah, bl1, acc1, 0, 0, 0);
        bf16x8 bh2 = *(const bf16x8*)&W1h[(size_t)((ntb + 2) * 16 + m) * 128 + k];
        bf16x8 bl2 = *(const bf16x8*)&W1l[(size_t)((ntb + 2) * 16 + m) * 128 + k];
        acc2 = __builtin_amdgcn_mfma_f32_16x16x32_bf16(ah, bh2, acc2, 0, 0, 0);
        acc2 = __builtin_amdgcn_mfma_f32_16x16x32_bf16(al, bh2, acc2, 0, 0, 0);
        acc2 = __builtin_amdgcn_mfma_f32_16x16x32_bf16(ah, bl2, acc2, 0, 0, 0);
        bf16x8 bh3 = *(const bf16x8*)&W1h[(size_t)((ntb + 3) * 16 + m) * 128 + k];
        bf16x8 bl3 = *(const bf16x8*)&W1l[(size_t)((ntb + 3) * 16 + m) * 128 + k];
        acc3 = __builtin_amdgcn_mfma_f32_16x16x32_bf16(ah, bh3, acc3, 0, 0, 0);
        acc3 = __builtin_amdgcn_mfma_f32_16x16x32_bf16(al, bh3, acc3, 0, 0, 0);
        acc3 = __builtin_amdgcn_mfma_f32_16x16x32_bf16(ah, bl3, acc3, 0, 0, 0);
      }
      // C/D layout: col = lane&15 (m), row = quad*4 + r  — NO dinv (deferred to gather)
      #pragma unroll
      for (int r = 0; r < 4; ++r) {
        int row = mt * 16 + (quad << 2) + r;
        int g = row0 + row;
        if (g < n) {
          H[(size_t)g * D + (ntb + 0) * 16 + m] = f2bf(acc0[r]);
          H[(size_t)g * D + (ntb + 1) * 16 + m] = f2bf(acc1[r]);
          H[(size_t)g * D + (ntb + 2) * 16 + m] = f2bf(acc2[r]);
          H[(size_t)g * D + (ntb + 3) * 16 + m] = f2bf(acc3[r]);
        }
      }
    }
  }
}

// ---------------- standalone atomic-free CSR fill ----------------

__global__ __launch_bounds__(256) void fill_kernel(const int* __restrict__ src,
                                                   const int* __restrict__ dst,
                                                   const int* __restrict__ ptr,
                                                   const int* __restrict__ rank,
                                                   int* __restrict__ csr, int E) {
  const int T8 = FUSED_GRID * 256 * 8;
  int t = blockIdx.x * 256 + threadIdx.x;
  const bool al16 = ((E & 3) == 0);
  for (int e0 = t * 8; e0 < E; e0 += T8) {
    if (e0 + 8 <= E && al16) {
      int4 d0 = ((const int4*)(dst + e0))[0];
      int4 d1 = ((const int4*)(dst + e0))[1];
      int4 s0 = ((const int4*)(src + e0))[0];
      int4 s1 = ((const int4*)(src + e0))[1];
      int4 r0 = ((const int4*)(rank + e0))[0];
      int4 r1 = ((const int4*)(rank + e0))[1];
      csr[ptr[d0.x] + r0.x] = s0.x;
      csr[ptr[d0.y] + r0.y] = s0.y;
      csr[ptr[d0.z] + r0.z] = s0.z;
      csr[ptr[d0.w] + r0.w] = s0.w;
      csr[ptr[d1.x] + r1.x] = s1.x;
      csr[ptr[d1.y] + r1.y] = s1.y;
      csr[ptr[d1.z] + r1.z] = s1.z;
      csr[ptr[d1.w] + r1.w] = s1.w;
    } else {
      for (int e = e0; e < E && e < e0 + 8; ++e)
        csr[ptr[dst[e]] + rank[e]] = src[e];
    }
  }
}

// ---------------- exclusive prefix scan of deg -> ptr ----------------

__global__ __launch_bounds__(256) void scan_blocksum_kernel(const int* __restrict__ deg, int n,
                                                            int* __restrict__ blockSums) {
  __shared__ int sm[256];
  int t = threadIdx.x;
  int i = blockIdx.x * 256 + t;
  sm[t] = (i < n) ? deg[i] : 0;
  __syncthreads();
  for (int off = 128; off > 0; off >>= 1) {
    if (t < off) sm[t] += sm[t + off];
    __syncthreads();
  }
  if (t == 0) blockSums[blockIdx.x] = sm[0];
}

// single block, 512 threads; nb <= 512
__global__ __launch_bounds__(512) void scan_top_kernel(int* __restrict__ blockSums, int nb) {
  __shared__ int sm[512];
  int t = threadIdx.x;
  int v = (t < nb) ? blockSums[t] : 0;
  sm[t] = v;
  __syncthreads();
  for (int off = 1; off < 512; off <<= 1) {
    int x = (t >= off) ? sm[t - off] : 0;
    __syncthreads();
    sm[t] += x;
    __syncthreads();
  }
  if (t < nb) blockSums[t] = sm[t] - v;  // exclusive
}

// also computes dinv, and writes ptr[n] = E (ptr stays an immutable start-offset array)
__global__ __launch_bounds__(256) void scan_write_kernel(const int* __restrict__ deg, int n,
                                                         const int* __restrict__ blockSums,
                                                         int* __restrict__ ptr,
                                                         float* __restrict__ dinv) {
  __shared__ int sm[256];
  int t = threadIdx.x;
  int i = blockIdx.x * 256 + t;
  int v = (i < n) ? deg[i] : 0;
  sm[t] = v;
  __syncthreads();
  for (int off = 1; off < 256; off <<= 1) {
    int x = (t >= off) ? sm[t - off] : 0;
    __syncthreads();
    sm[t] += x;
    __syncthreads();
  }
  if (i < n) {
    int ex = blockSums[blockIdx.x] + sm[t] - v;
    ptr[i] = ex;                             // exclusive prefix (row start)
    dinv[i] = 1.0f / sqrtf((float)(v + 1));  // +1: self-loop
    if (i == n - 1) ptr[n] = ex + v;         // = E
  }
}

// ---------------- legacy fp32 VALU GEMM body (fallback path only) ----------------

__device__ __forceinline__ void gemm_body(const float* __restrict__ X,
                                          const float* __restrict__ W,
                                          const float* __restrict__ dinv,
                                          unsigned short* __restrict__ H, int n,
                                          int bid, int nblocks,
                                          float* __restrict__ Ws, float* __restrict__ Xs) {
  const int tid = threadIdx.x;
  const int tx = tid & 31;
  const int ty = tid >> 5;
  const int ntiles = (n + 31) >> 5;

  for (int tile = bid; tile < ntiles; tile += nblocks) {
    const int row0 = tile << 5;
    const int rows_here = min(32, n - row0);
    __syncthreads();
    {
      const float4* Xg = (const float4*)(X + (size_t)row0 * D);
      int tmax = rows_here * 32;
      for (int t = tid; t < tmax; t += 256) ((float4*)Xs)[t] = Xg[t];
    }
    float acc[4][4] = {{0.f}};
    #pragma unroll
    for (int kt = 0; kt < 128; kt += 64) {
      __syncthreads();
      for (int t = tid; t < 2048; t += 256) {
        int j  = t >> 4;
        int k4 = (t & 15) << 2;
        float4 w = ((const float4*)W)[j * 32 + (kt >> 2) + (t & 15)];
        Ws[(k4 + 0) * WS_PAD + j] = w.x;
        Ws[(k4 + 1) * WS_PAD + j] = w.y;
        Ws[(k4 + 2) * WS_PAD + j] = w.z;
        Ws[(k4 + 3) * WS_PAD + j] = w.w;
      }
      __syncthreads();
      #pragma unroll 4
      for (int k = 0; k < 64; ++k) {
        float4 w = *(const float4*)&Ws[k * WS_PAD + (tx << 2)];
        #pragma unroll
        for (int r = 0; r < 4; ++r) {
          float xv = Xs[(ty + 8 * r) * 128 + (kt + k)];
          acc[r][0] += xv * w.x;
          acc[r][1] += xv * w.y;
          acc[r][2] += xv * w.z;
          acc[r][3] += xv * w.w;
        }
      }
    }
    #pragma unroll
    for (int r = 0; r < 4; ++r) {
      int row = row0 + ty + 8 * r;
      if (row < n) {
        float s = dinv[row];
        unsigned h0 = f2bf(s * acc[r][0]);
        unsigned h1 = f2bf(s * acc[r][1]);
        unsigned h2 = f2bf(s * acc[r][2]);
        unsigned h3 = f2bf(s * acc[r][3]);
        ((uint2*)(H + (size_t)row * D))[tx] = make_uint2(h0 | (h1 << 16), h2 | (h3 << 16));
      }
    }
  }
}

// ---------------- legacy kernels (fallback path only) ----------------

__global__ __launch_bounds__(256) void count_legacy_kernel(const int* __restrict__ dst, int E,
                                                           int* __restrict__ deg) {
  int e = blockIdx.x * 256 + threadIdx.x;
  if (e < E) atomicAdd(&deg[dst[e]], 1);
}

__global__ __launch_bounds__(256) void fused_fill_gemm_kernel(
    const int* __restrict__ src, const int* __restrict__ dst,
    int* __restrict__ ptr, int* __restrict__ csr, int E,
    const float* __restrict__ X, const float* __restrict__ W,
    const float* __restrict__ dinv, unsigned short* __restrict__ H, int n) {
  __shared__ float Ws[64 * WS_PAD];
  __shared__ float Xs[32 * 128];
  int sub = blockIdx.x & 7;
  if (sub < 2) {
    int fb = (blockIdx.x >> 3) * 2 + sub;
    int stride = 512 * 256;
    for (int e = fb * 256 + threadIdx.x; e < E; e += stride) {
      int d = dst[e];
      int pos = atomicAdd(&ptr[d], 1);
      csr[pos] = src[e];
    }
  } else {
    int gb = (blockIdx.x >> 3) * 6 + (sub - 2);
    gemm_body(X, W, dinv, H, n, gb, 1536, Ws, Xs);
  }
}

__global__ __launch_bounds__(256) void gemm128_kernel(const float* __restrict__ X,
                                                      const float* __restrict__ W,
                                                      const float* __restrict__ dinv,
                                                      unsigned short* __restrict__ H, int n) {
  __shared__ float Ws[64 * WS_PAD];
  __shared__ float Xs[32 * 128];
  gemm_body(X, W, dinv, H, n, blockIdx.x, gridDim.x, Ws, Xs);
}

__device__ __forceinline__ void gather_row_legacy(const int* __restrict__ csr, int start, int end,
                                                  const unsigned* __restrict__ Hu,
                                                  int i, int lane, float& ax, float& ay) {
  unsigned v = Hu[(size_t)i * 64 + lane];
  ax = __uint_as_float(v << 16);
  ay = __uint_as_float(v & 0xFFFF0000u);
  for (int e = start; e < end; ++e) {
    unsigned w = Hu[(size_t)csr[e] * 64 + lane];
    ax += __uint_as_float(w << 16);
    ay += __uint_as_float(w & 0xFFFF0000u);
  }
}

__global__ __launch_bounds__(256, 8) void gather_kernel_old(const int* __restrict__ csr,
                                                            const int* __restrict__ rend,
                                                            const float* __restrict__ dinv,
                                                            const unsigned* __restrict__ Hu,
                                                            const float* __restrict__ bias,
                                                            const float* __restrict__ perturb,
                                                            float* __restrict__ out, int n) {
  int i = (blockIdx.x << 2) + (threadIdx.x >> 6);
  if (i >= n) return;
  int lane = threadIdx.x & 63;
  int start = (i == 0) ? 0 : rend[i - 1];
  float ax, ay;
  gather_row_legacy(csr, start, rend[i], Hu, i, lane, ax, ay);
  float di = dinv[i];
  float2 p = ((const float2*)(perturb + (size_t)i * D))[lane];
  float2 o;
  o.x = bias[2 * lane + 0] + p.x + di * ax;
  o.y = bias[2 * lane + 1] + p.y + di * ay;
  ((float2*)(out + (size_t)i * D))[lane] = o;
}

// ---------------- weighted quad gather (gather1 in gather_gemm): 4 rows/wave, uint4 ----------------
// rows are RAW (no dinv); multiply each by dinv[src] in fp32 during gather.

__device__ __forceinline__ void gather_quad_w(const int* __restrict__ csr, int start, int end,
                                              const uint4* __restrict__ Hu4,
                                              const float* __restrict__ dinv,
                                              int i, int sub, float acc[8]) {
  float ds = dinv[i];
  uint4 v = Hu4[(size_t)i * 16 + sub];
  acc[0] = ds * bflo(v.x); acc[1] = ds * bfhi(v.x);
  acc[2] = ds * bflo(v.y); acc[3] = ds * bfhi(v.y);
  acc[4] = ds * bflo(v.z); acc[5] = ds * bfhi(v.z);
  acc[6] = ds * bflo(v.w); acc[7] = ds * bfhi(v.w);
  int e = start;
  while (__ballot(e < end)) {
    uint4 w0 = {0u, 0u, 0u, 0u}, w1 = {0u, 0u, 0u, 0u};
    float d0 = 0.f, d1 = 0.f;
    if (e < end)     { int j = csr[e];     w0 = Hu4[(size_t)j * 16 + sub]; d0 = dinv[j]; }
    if (e + 1 < end) { int j = csr[e + 1]; w1 = Hu4[(size_t)j * 16 + sub]; d1 = dinv[j]; }
    acc[0] += d0 * bflo(w0.x); acc[1] += d0 * bfhi(w0.x);
    acc[2] += d0 * bflo(w0.y); acc[3] += d0 * bfhi(w0.y);
    acc[4] += d0 * bflo(w0.z); acc[5] += d0 * bfhi(w0.z);
    acc[6] += d0 * bflo(w0.w); acc[7] += d0 * bfhi(w0.w);
    acc[0] += d1 * bflo(w1.x); acc[1] += d1 * bfhi(w1.x);
    acc[2] += d1 * bflo(w1.y); acc[3] += d1 * bfhi(w1.y);
    acc[4] += d1 * bflo(w1.z); acc[5] += d1 * bfhi(w1.z);
    acc[6] += d1 * bflo(w1.w); acc[7] += d1 * bfhi(w1.w);
    e += 2;
  }
}

// ---------------- gather2: COLUMN-SLICED, XCD-L2-resident ----------------
// A2 is stored slice-major: A2s[s][i][16 cols], slice s region = n*32B = 3.2MB < 4MiB L2.
// slice = blockIdx & 7 -> under round-robin block->XCD dispatch, all blocks of slice s
// run on XCD s, so the slice stays L2-resident and neighbor reads never cross the fabric.
// (Correctness does NOT depend on the mapping — only speed.) Lane-pair layout: pair
// p=lane>>1 owns node i, half=lane&1 covers 16B of the 32B row-slice -> one VMEM
// instruction reads 32 different neighbor row-slices.

__global__ __launch_bounds__(256, 8) void gather2_sliced_kernel(
    const int* __restrict__ csr, const int* __restrict__ rptr,
    const float* __restrict__ dinv, const unsigned short* __restrict__ A2s,
    const float* __restrict__ bias, const float* __restrict__ perturb,
    float* __restrict__ out, int n) {
  const int s = blockIdx.x & 7;       // slice (XCD-pinned by round-robin)
  const int tile = blockIdx.x >> 3;   // 128-node tile
  const int tid = threadIdx.x;
  const int wv = tid >> 6;
  const int lane = tid & 63;
  const int pair = lane >> 1;         // 0..31
  const int half = lane & 1;          // which 16B of the 32B slice-row
  int i = (tile << 7) + (wv << 5) + pair;
  bool valid = i < n;
  int ic = valid ? i : (n - 1);
  int start = rptr[ic];
  int end = valid ? rptr[ic + 1] : start;
  const uint4* base = (const uint4*)(A2s + (size_t)s * n * 16);  // 2 uint4 per row

  uint4 v = base[(size_t)ic * 2 + half];  // self-loop term (A2 prescaled by dinv[src])
  float acc[8];
  acc[0] = bflo(v.x); acc[1] = bfhi(v.x);
  acc[2] = bflo(v.y); acc[3] = bfhi(v.y);
  acc[4] = bflo(v.z); acc[5] = bfhi(v.z);
  acc[6] = bflo(v.w); acc[7] = bfhi(v.w);
  int e = start;
  while (__ballot(e < end)) {
    uint4 w0 = {0u, 0u, 0u, 0u}, w1 = {0u, 0u, 0u, 0u};
    if (e < end)     w0 = base[(size_t)csr[e] * 2 + half];
    if (e + 1 < end) w1 = base[(size_t)csr[e + 1] * 2 + half];
    acc[0] += bflo(w0.x); acc[1] += bfhi(w0.x);
    acc[2] += bflo(w0.y); acc[3] += bfhi(w0.y);
    acc[4] += bflo(w0.z); acc[5] += bfhi(w0.z);
    acc[6] += bflo(w0.w); acc[7] += bfhi(w0.w);
    acc[0] += bflo(w1.x); acc[1] += bfhi(w1.x);
    acc[2] += bflo(w1.y); acc[3] += bfhi(w1.y);
    acc[4] += bflo(w1.z); acc[5] += bfhi(w1.z);
    acc[6] += bflo(w1.w); acc[7] += bfhi(w1.w);
    e += 2;
  }
  if (valid) {
    float di = dinv[i];
    int col = (s << 4) + (half << 3);
    float4 b0 = *(const float4*)&bias[col];
    float4 b1 = *(const float4*)&bias[col + 4];
    float4 p0 = *(const float4*)&perturb[(size_t)i * D + col];
    float4 p1 = *(const float4*)&perturb[(size_t)i * D + col + 4];
    float4 o0, o1;
    o0.x = b0.x + p0.x + di * acc[0];
    o0.y = b0.y + p0.y + di * acc[1];
    o0.z = b0.z + p0.z + di * acc[2];
    o0.w = b0.w + p0.w + di * acc[3];
    o1.x = b1.x + p1.x + di * acc[4];
    o1.y = b1.y + p1.y + di * acc[5];
    o1.z = b1.z + p1.z + di * acc[6];
    o1.w = b1.w + p1.w + di * acc[7];
    *(float4*)&out[(size_t)i * D + col] = o0;
    *(float4*)&out[(size_t)i * D + col + 4] = o1;
  }
}

// ---------------- fused gather1 (dinv-weighted) + GEMM2 (MFMA bf16) ----------------
// Epilogue now writes A2 SLICE-MAJOR: A2s[s][i][16] with s = column/16.

#define GG_PITCH 136

__global__ __launch_bounds__(512, 8) void gather_gemm_kernel(
    const int* __restrict__ csr, const int* __restrict__ rptr,
    const float* __restrict__ dinv, const unsigned* __restrict__ Hu,
    const float* __restrict__ bias, const float* __restrict__ perturb,
    const unsigned short* __restrict__ W2bf, unsigned short* __restrict__ H2s, int n) {
  __shared__ unsigned short Ts[32 * GG_PITCH];  // 8.5 KB
  const int tid = threadIdx.x;
  const int wv = tid >> 6;
  const int lane = tid & 63;
  const int base = blockIdx.x << 5;  // 32 nodes per block

  // phase 1: weighted quad gather over RAW A1 — wave wv covers rows [wv*4, wv*4+4)
  {
    const int g = lane >> 4;
    const int sub = lane & 15;
    int row_in_block = (wv << 2) + g;
    int i = base + row_in_block;
    bool valid = i < n;
    int ic = valid ? i : (n - 1);
    int start = rptr[ic];
    int end = valid ? rptr[ic + 1] : start;
    float acc[8];
    gather_quad_w(csr, start, end, (const uint4*)Hu, dinv, ic, sub, acc);
    if (valid) {
      float di = dinv[i];
      float4 b0 = *(const float4*)&bias[sub * 8];
      float4 b1 = *(const float4*)&bias[sub * 8 + 4];
      float4 p0 = *(const float4*)&perturb[(size_t)i * D + sub * 8];
      float4 p1 = *(const float4*)&perturb[(size_t)i * D + sub * 8 + 4];
      unsigned q0 = (unsigned)f2bf(b0.x + p0.x + di * acc[0]) |
                    ((unsigned)f2bf(b0.y + p0.y + di * acc[1]) << 16);
      unsigned q1 = (unsigned)f2bf(b0.z + p0.z + di * acc[2]) |
                    ((unsigned)f2bf(b0.w + p0.w + di * acc[3]) << 16);
      unsigned q2 = (unsigned)f2bf(b1.x + p1.x + di * acc[4]) |
                    ((unsigned)f2bf(b1.y + p1.y + di * acc[5]) << 16);
      unsigned q3 = (unsigned)f2bf(b1.z + p1.z + di * acc[6]) |
                    ((unsigned)f2bf(b1.w + p1.w + di * acc[7]) << 16);
      uint4 pack = make_uint4(q0, q1, q2, q3);
      *(uint4*)&Ts[row_in_block * GG_PITCH + sub * 8] = pack;
    }
  }
  __syncthreads();

  // phase 2: R[32][128] = Ts @ W2bf^T ; wave wv: m-tile = wv>>2, n-tiles {wv&3, (wv&3)+4}
  const int mt = wv >> 2;
  const int nt0 = wv & 3;
  const int m = lane & 15;
  const int quad = lane >> 4;  // 0..3
  const unsigned short* Wrow0 = W2bf + (size_t)(nt0 * 16 + m) * 128;
  const unsigned short* Wrow1 = W2bf + (size_t)((nt0 + 4) * 16 + m) * 128;
  f32x4 acc0 = {0.f, 0.f, 0.f, 0.f};
  f32x4 acc1 = {0.f, 0.f, 0.f, 0.f};
  #pragma unroll
  for (int s = 0; s < 4; ++s) {
    int k = (s << 5) + (quad << 3);
    bf16x8 a  = *(const bf16x8*)&Ts[(mt * 16 + m) * GG_PITCH + k];
    bf16x8 b0 = *(const bf16x8*)&Wrow0[k];
    bf16x8 b1 = *(const bf16x8*)&Wrow1[k];
    acc0 = __builtin_amdgcn_mfma_f32_16x16x32_bf16(a, b0, acc0, 0, 0, 0);
    acc1 = __builtin_amdgcn_mfma_f32_16x16x32_bf16(a, b1, acc1, 0, 0, 0);
  }
  // C/D layout: col = lane&15, row = quad*4 + reg ; slice-major A2 write, prescaled by dinv
  #pragma unroll
  for (int r = 0; r < 4; ++r) {
    int row = mt * 16 + (quad << 2) + r;
    int gg = base + row;
    if (gg < n) {
      float sc = dinv[gg];
      H2s[(size_t)nt0 * n * 16 + (size_t)gg * 16 + m]       = f2bf(sc * acc0[r]);
      H2s[(size_t)(nt0 + 4) * n * 16 + (size_t)gg * 16 + m] = f2bf(sc * acc1[r]);
    }
  }
}

// ---------------- launch ----------------

extern "C" void kernel_launch(void* const* d_in, const int* in_sizes, int n_in,
                              void* d_out, int out_size, void* d_ws, size_t ws_size,
                              hipStream_t stream) {
  const float* x  = (const float*)d_in[0];
  const int*   ei = (const int*)d_in[1];
  const float* pf = (const float*)d_in[2];
  const float* pl = (const float*)d_in[3];
  const float* W1 = (const float*)d_in[4];
  const float* b1 = (const float*)d_in[5];
  const float* W2 = (const float*)d_in[6];
  const float* b2 = (const float*)d_in[7];
  float* out = (float*)d_out;

  const int n = in_sizes[0] / D;
  const int E = in_sizes[1] / 2;
  const int* src = ei;      // edge_index[0]
  const int* dst = ei + E;  // edge_index[1]

  // workspace layout
  int*   deg       = (int*)d_ws;                     // [n]
  float* dinv      = (float*)d_ws + n;               // [n]
  int*   ptr       = (int*)d_ws + 2 * n;             // [n+1] (start offsets; immutable in fused path)
  int*   blockSums = (int*)d_ws + 3 * n + 1;         // [<=512]
  int*   csr       = (int*)d_ws + 3 * n + 1 + 512;   // [E]
  size_t a1_off = ((size_t)(3 * n + 1 + 512 + E) * 4 + 255) & ~(size_t)255;
  unsigned short* A1 = (unsigned short*)((char*)d_ws + a1_off);
  unsigned short* A2 = A1 + (size_t)n * D;       // slice-major in fused path
  unsigned short* W2bf = A2 + (size_t)n * D;     // [128*128] bf16, 32 KB
  unsigned short* W1h  = W2bf + 128 * 128;       // [128*128] bf16, 32 KB
  unsigned short* W1l  = W1h + 128 * 128;        // [128*128] bf16, 32 KB
  int* rank = (int*)A2;                          // [E] aliases A2 (dead until gather_gemm)
  size_t needed = a1_off + (2 * (size_t)n * D + 3 * 128 * 128) * sizeof(unsigned short);
  const bool fused_l2 = (ws_size >= needed);  // constant across calls -> capture-safe

  const int nb_n = (n + 255) / 256;
  const int nb_e = (E + 255) / 256;
  const int nb_g4 = (n + 3) / 4;

  hipMemsetAsync(deg, 0, (size_t)n * sizeof(int), stream);

  if (fused_l2) {
    // W tables first (tiny); then count+rank || GEMM1_raw fully overlapped
    wprep_kernel<<<16, 256, 0, stream>>>(W2, W2bf, W1, W1h, W1l);
    count_gemm1_kernel<<<FUSED_GRID, 256, 0, stream>>>(dst, E, deg, rank, x, W1h, W1l, A1, n);
    scan_blocksum_kernel<<<nb_n, 256, 0, stream>>>(deg, n, blockSums);
    scan_top_kernel<<<1, 512, 0, stream>>>(blockSums, nb_n);
    scan_write_kernel<<<nb_n, 256, 0, stream>>>(deg, n, blockSums, ptr, dinv);
    // atomic-free fill (standalone, ~bandwidth-bound)
    fill_kernel<<<FUSED_GRID, 256, 0, stream>>>(src, dst, ptr, rank, csr, E);
    // gather1 (dinv-weighted over raw A1) + GEMM2 -> A2 slice-major
    gather_gemm_kernel<<<(n + 31) / 32, 512, 0, stream>>>(csr, ptr, dinv, (const unsigned*)A1,
                                                          b1, pf, W2bf, A2, n);
    // gather2: column-sliced, XCD-L2-resident
    int ntiles2 = (n + 127) / 128;
    gather2_sliced_kernel<<<ntiles2 * 8, 256, 0, stream>>>(csr, ptr, dinv, A2, b2, pl, out, n);
  } else {
    // fallback: fp32 VALU gemm, atomic fill (ptr becomes row_end), legacy gathers
    count_legacy_kernel<<<nb_e, 256, 0, stream>>>(dst, E, deg);
    scan_blocksum_kernel<<<nb_n, 256, 0, stream>>>(deg, n, blockSums);
    scan_top_kernel<<<1, 512, 0, stream>>>(blockSums, nb_n);
    scan_write_kernel<<<nb_n, 256, 0, stream>>>(deg, n, blockSums, ptr, dinv);
    fused_fill_gemm_kernel<<<FUSED_GRID, 256, 0, stream>>>(src, dst, ptr, csr, E, x, W1, dinv, A1, n);
    gather_kernel_old<<<nb_g4, 256, 0, stream>>>(csr, ptr, dinv, (const unsigned*)A1, b1, pf, out, n);
    gemm128_kernel<<<1024, 256, 0, stream>>>(out, W2, dinv, A1, n);
    gather_kernel_old<<<nb_g4, 256, 0, stream>>>(csr, ptr, dinv, (const unsigned*)A1, b2, pl, out, n);
  }
}

// Round 12
// 477.276 us; speedup vs baseline: 1.0980x; 1.0980x over previous
//
#include <hip/hip_runtime.h>
#include <math.h>

#define D 128
#define WS_PAD 132  // 128+4: breaks stride-128 bank pattern, keeps 16B align

typedef short bf16x8 __attribute__((ext_vector_type(8)));  // 8 bf16 in 4 VGPRs
typedef float f32x4 __attribute__((ext_vector_type(4)));

__device__ __forceinline__ unsigned short f2bf(float f) {
  unsigned u = __float_as_uint(f);
  u += 0x7FFFu + ((u >> 16) & 1u);  // round-to-nearest-even
  return (unsigned short)(u >> 16);
}

__device__ __forceinline__ float bf2f(unsigned short h) {
  return __uint_as_float(((unsigned)h) << 16);
}

__device__ __forceinline__ float bflo(unsigned u) { return __uint_as_float(u << 16); }
__device__ __forceinline__ float bfhi(unsigned u) { return __uint_as_float(u & 0xFFFF0000u); }

// ---------------- weight-table prep (16 blocks, runs before count||GEMM1) ----------------

__global__ __launch_bounds__(256) void wprep_kernel(const float* __restrict__ W2,
                                                    unsigned short* __restrict__ W2bf,
                                                    const float* __restrict__ W1,
                                                    unsigned short* __restrict__ W1h,
                                                    unsigned short* __restrict__ W1l) {
  int which = blockIdx.x;  // 0..15
  if (which < 8) {
    int t = which * 256 + threadIdx.x;  // 0..2047
    #pragma unroll
    for (int q = 0; q < 2; ++q) {
      int idx = t + q * 2048;  // float4 index, 0..4095
      float4 w = ((const float4*)W2)[idx];
      ushort4 o;
      o.x = f2bf(w.x); o.y = f2bf(w.y); o.z = f2bf(w.z); o.w = f2bf(w.w);
      ((ushort4*)W2bf)[idx] = o;
    }
  } else {
    int t = (which - 8) * 256 + threadIdx.x;
    #pragma unroll
    for (int q = 0; q < 2; ++q) {
      int idx = t + q * 2048;
      float4 w = ((const float4*)W1)[idx];
      ushort4 hi, lo;
      hi.x = f2bf(w.x); lo.x = f2bf(w.x - bf2f(hi.x));
      hi.y = f2bf(w.y); lo.y = f2bf(w.y - bf2f(hi.y));
      hi.z = f2bf(w.z); lo.z = f2bf(w.z - bf2f(hi.z));
      hi.w = f2bf(w.w); lo.w = f2bf(w.w - bf2f(hi.w));
      ((ushort4*)W1h)[idx] = hi;
      ((ushort4*)W1l)[idx] = lo;
    }
  }
}

// ---------------- fused: degree count + rank (atomic-bound) || GEMM1_raw (MFMA) ----------------
// R11: rebalanced 5:3 (count 1280 blocks, GEMM1 768). GEMM1 is bandwidth-bound with
// ~3x slack; count side gets +25% waves in case its atomic issue is parallelism-limited.

#define FUSED_GRID 2048
#define G1_PITCH 136

__global__ __launch_bounds__(256) void count_gemm1_kernel(
    const int* __restrict__ dst, int E, int* __restrict__ deg, int* __restrict__ rank,
    const float* __restrict__ X,
    const unsigned short* __restrict__ W1h, const unsigned short* __restrict__ W1l,
    unsigned short* __restrict__ H, int n) {
  __shared__ unsigned short Ths[32 * G1_PITCH];  // 8.7 KB
  __shared__ unsigned short Tls[32 * G1_PITCH];  // 8.7 KB
  int sub = blockIdx.x & 7;
  if (sub < 5) {
    // count + rank: 1280 blocks, 4 edges/thread, grid-strided
    int cb = (blockIdx.x >> 3) * 5 + sub;
    const int T4 = 1280 * 256 * 4;
    int t = cb * 256 + threadIdx.x;
    const bool al16 = ((E & 3) == 0);
    for (int e0 = t * 4; e0 < E; e0 += T4) {
      if (e0 + 4 <= E && al16) {
        int4 d = *(const int4*)(dst + e0);
        int r0 = atomicAdd(&deg[d.x], 1);
        int r1 = atomicAdd(&deg[d.y], 1);
        int r2 = atomicAdd(&deg[d.z], 1);
        int r3 = atomicAdd(&deg[d.w], 1);
        *(int4*)(rank + e0) = make_int4(r0, r1, r2, r3);
      } else {
        for (int e = e0; e < E && e < e0 + 4; ++e) rank[e] = atomicAdd(&deg[dst[e]], 1);
      }
    }
  } else {
    // GEMM1_raw: 768 blocks, 32 rows per tile, grid-strided; bf16x3 fp32-accurate
    int gb = (blockIdx.x >> 3) * 3 + (sub - 5);
    const int tid = threadIdx.x;
    const int wv = tid >> 6;       // 0..3
    const int lane = tid & 63;
    const int m = lane & 15;
    const int quad = lane >> 4;    // 0..3
    const int mt = wv >> 1;        // 0..1  (16-row m-tile)
    const int ntb = (wv & 1) * 4;  // n-tile base: 4 consecutive 16-col tiles
    const int ntiles = (n + 31) >> 5;

    for (int tile = gb; tile < ntiles; tile += 768) {
      const int row0 = tile << 5;
      const int rows_here = min(32, n - row0);
      __syncthreads();  // protect LDS from previous iteration's readers
      {
        const float4* Xg = (const float4*)(X + (size_t)row0 * D);
        int tmax = rows_here * 32;
        for (int t = tid; t < tmax; t += 256) {
          float4 xv = Xg[t];
          int r = t >> 5, c4 = (t & 31) << 2;
          ushort4 hi, lo;
          hi.x = f2bf(xv.x); lo.x = f2bf(xv.x - bf2f(hi.x));
          hi.y = f2bf(xv.y); lo.y = f2bf(xv.y - bf2f(hi.y));
          hi.z = f2bf(xv.z); lo.z = f2bf(xv.z - bf2f(hi.z));
          hi.w = f2bf(xv.w); lo.w = f2bf(xv.w - bf2f(hi.w));
          *(ushort4*)&Ths[r * G1_PITCH + c4] = hi;
          *(ushort4*)&Tls[r * G1_PITCH + c4] = lo;
        }
      }
      __syncthreads();

      f32x4 acc0 = {0.f, 0.f, 0.f, 0.f};
      f32x4 acc1 = {0.f, 0.f, 0.f, 0.f};
      f32x4 acc2 = {0.f, 0.f, 0.f, 0.f};
      f32x4 acc3 = {0.f, 0.f, 0.f, 0.f};
      #pragma unroll
      for (int s = 0; s < 4; ++s) {
        int k = (s << 5) + (quad << 3);
        bf16x8 ah = *(const bf16x8*)&Ths[(mt * 16 + m) * G1_PITCH + k];
        bf16x8 al = *(const bf16x8*)&Tls[(mt * 16 + m) * G1_PITCH + k];
        bf16x8 bh0 = *(const bf16x8*)&W1h[(size_t)((ntb + 0) * 16 + m) * 128 + k];
        bf16x8 bl0 = *(const bf16x8*)&W1l[(size_t)((ntb + 0) * 16 + m) * 128 + k];
        acc0 = __builtin_amdgcn_mfma_f32_16x16x32_bf16(ah, bh0, acc0, 0, 0, 0);
        acc0 = __builtin_amdgcn_mfma_f32_16x16x32_bf16(al, bh0, acc0, 0, 0, 0);
        acc0 = __builtin_amdgcn_mfma_f32_16x16x32_bf16(ah, bl0, acc0, 0, 0, 0);
        bf16x8 bh1 = *(const bf16x8*)&W1h[(size_t)((ntb + 1) * 16 + m) * 128 + k];
        bf16x8 bl1 = *(const bf16x8*)&W1l[(size_t)((ntb + 1) * 16 + m) * 128 + k];
        acc1 = __builtin_amdgcn_mfma_f32_16x16x32_bf16(ah, bh1, acc1, 0, 0, 0);
        acc1 = __builtin_amdgcn_mfma_f32_16x16x32_bf16(al, bh1, acc1, 0, 0, 0);
        acc1 = __builtin_amdgcn_mfma_f32_16x16x32_bf16(ah, bl1, acc1, 0, 0, 0);
        bf16x8 bh2 = *(const bf16x8*)&W1h[(size_t)((ntb + 2) * 16 + m) * 128 + k];
        bf16x8 bl2 = *(const bf16x8*)&W1l[(size_t)((ntb + 2) * 16 + m) * 128 + k];
        acc2 = __builtin_amdgcn_mfma_f32_16x16x32_bf16(ah, bh2, acc2, 0, 0, 0);
        acc2 = __builtin_amdgcn_mfma_f32_16x16x32_bf16(al, bh2, acc2, 0, 0, 0);
        acc2 = __builtin_amdgcn_mfma_f32_16x16x32_bf16(ah, bl2, acc2, 0, 0, 0);
        bf16x8 bh3 = *(const bf16x8*)&W1h[(size_t)((ntb + 3) * 16 + m) * 128 + k];
        bf16x8 bl3 = *(const bf16x8*)&W1l[(size_t)((ntb + 3) * 16 + m) * 128 + k];
        acc3 = __builtin_amdgcn_mfma_f32_16x16x32_bf16(ah, bh3, acc3, 0, 0, 0);
        acc3 = __builtin_amdgcn_mfma_f32_16x16x32_bf16(al, bh3, acc3, 0, 0, 0);
        acc3 = __builtin_amdgcn_mfma_f32_16x16x32_bf16(ah, bl3, acc3, 0, 0, 0);
      }
      // C/D layout: col = lane&15 (m), row = quad*4 + r  — NO dinv (deferred to gather)
      #pragma unroll
      for (int r = 0; r < 4; ++r) {
        int row = mt * 16 + (quad << 2) + r;
        int g = row0 + row;
        if (g < n) {
          H[(size_t)g * D + (ntb + 0) * 16 + m] = f2bf(acc0[r]);
          H[(size_t)g * D + (ntb + 1) * 16 + m] = f2bf(acc1[r]);
          H[(size_t)g * D + (ntb + 2) * 16 + m] = f2bf(acc2[r]);
          H[(size_t)g * D + (ntb + 3) * 16 + m] = f2bf(acc3[r]);
        }
      }
    }
  }
}

// ---------------- standalone atomic-free CSR fill ----------------

__global__ __launch_bounds__(256) void fill_kernel(const int* __restrict__ src,
                                                   const int* __restrict__ dst,
                                                   const int* __restrict__ ptr,
                                                   const int* __restrict__ rank,
                                                   int* __restrict__ csr, int E) {
  const int T8 = FUSED_GRID * 256 * 8;
  int t = blockIdx.x * 256 + threadIdx.x;
  const bool al16 = ((E & 3) == 0);
  for (int e0 = t * 8; e0 < E; e0 += T8) {
    if (e0 + 8 <= E && al16) {
      int4 d0 = ((const int4*)(dst + e0))[0];
      int4 d1 = ((const int4*)(dst + e0))[1];
      int4 s0 = ((const int4*)(src + e0))[0];
      int4 s1 = ((const int4*)(src + e0))[1];
      int4 r0 = ((const int4*)(rank + e0))[0];
      int4 r1 = ((const int4*)(rank + e0))[1];
      csr[ptr[d0.x] + r0.x] = s0.x;
      csr[ptr[d0.y] + r0.y] = s0.y;
      csr[ptr[d0.z] + r0.z] = s0.z;
      csr[ptr[d0.w] + r0.w] = s0.w;
      csr[ptr[d1.x] + r1.x] = s1.x;
      csr[ptr[d1.y] + r1.y] = s1.y;
      csr[ptr[d1.z] + r1.z] = s1.z;
      csr[ptr[d1.w] + r1.w] = s1.w;
    } else {
      for (int e = e0; e < E && e < e0 + 8; ++e)
        csr[ptr[dst[e]] + rank[e]] = src[e];
    }
  }
}

// ---------------- exclusive prefix scan of deg -> ptr ----------------

__global__ __launch_bounds__(256) void scan_blocksum_kernel(const int* __restrict__ deg, int n,
                                                            int* __restrict__ blockSums) {
  __shared__ int sm[256];
  int t = threadIdx.x;
  int i = blockIdx.x * 256 + t;
  sm[t] = (i < n) ? deg[i] : 0;
  __syncthreads();
  for (int off = 128; off > 0; off >>= 1) {
    if (t < off) sm[t] += sm[t + off];
    __syncthreads();
  }
  if (t == 0) blockSums[blockIdx.x] = sm[0];
}

// single block, 512 threads; nb <= 512
__global__ __launch_bounds__(512) void scan_top_kernel(int* __restrict__ blockSums, int nb) {
  __shared__ int sm[512];
  int t = threadIdx.x;
  int v = (t < nb) ? blockSums[t] : 0;
  sm[t] = v;
  __syncthreads();
  for (int off = 1; off < 512; off <<= 1) {
    int x = (t >= off) ? sm[t - off] : 0;
    __syncthreads();
    sm[t] += x;
    __syncthreads();
  }
  if (t < nb) blockSums[t] = sm[t] - v;  // exclusive
}

// also computes dinv, and writes ptr[n] = E (ptr stays an immutable start-offset array)
__global__ __launch_bounds__(256) void scan_write_kernel(const int* __restrict__ deg, int n,
                                                         const int* __restrict__ blockSums,
                                                         int* __restrict__ ptr,
                                                         float* __restrict__ dinv) {
  __shared__ int sm[256];
  int t = threadIdx.x;
  int i = blockIdx.x * 256 + t;
  int v = (i < n) ? deg[i] : 0;
  sm[t] = v;
  __syncthreads();
  for (int off = 1; off < 256; off <<= 1) {
    int x = (t >= off) ? sm[t - off] : 0;
    __syncthreads();
    sm[t] += x;
    __syncthreads();
  }
  if (i < n) {
    int ex = blockSums[blockIdx.x] + sm[t] - v;
    ptr[i] = ex;                             // exclusive prefix (row start)
    dinv[i] = 1.0f / sqrtf((float)(v + 1));  // +1: self-loop
    if (i == n - 1) ptr[n] = ex + v;         // = E
  }
}

// ---------------- legacy fp32 VALU GEMM body (fallback path only) ----------------

__device__ __forceinline__ void gemm_body(const float* __restrict__ X,
                                          const float* __restrict__ W,
                                          const float* __restrict__ dinv,
                                          unsigned short* __restrict__ H, int n,
                                          int bid, int nblocks,
                                          float* __restrict__ Ws, float* __restrict__ Xs) {
  const int tid = threadIdx.x;
  const int tx = tid & 31;
  const int ty = tid >> 5;
  const int ntiles = (n + 31) >> 5;

  for (int tile = bid; tile < ntiles; tile += nblocks) {
    const int row0 = tile << 5;
    const int rows_here = min(32, n - row0);
    __syncthreads();
    {
      const float4* Xg = (const float4*)(X + (size_t)row0 * D);
      int tmax = rows_here * 32;
      for (int t = tid; t < tmax; t += 256) ((float4*)Xs)[t] = Xg[t];
    }
    float acc[4][4] = {{0.f}};
    #pragma unroll
    for (int kt = 0; kt < 128; kt += 64) {
      __syncthreads();
      for (int t = tid; t < 2048; t += 256) {
        int j  = t >> 4;
        int k4 = (t & 15) << 2;
        float4 w = ((const float4*)W)[j * 32 + (kt >> 2) + (t & 15)];
        Ws[(k4 + 0) * WS_PAD + j] = w.x;
        Ws[(k4 + 1) * WS_PAD + j] = w.y;
        Ws[(k4 + 2) * WS_PAD + j] = w.z;
        Ws[(k4 + 3) * WS_PAD + j] = w.w;
      }
      __syncthreads();
      #pragma unroll 4
      for (int k = 0; k < 64; ++k) {
        float4 w = *(const float4*)&Ws[k * WS_PAD + (tx << 2)];
        #pragma unroll
        for (int r = 0; r < 4; ++r) {
          float xv = Xs[(ty + 8 * r) * 128 + (kt + k)];
          acc[r][0] += xv * w.x;
          acc[r][1] += xv * w.y;
          acc[r][2] += xv * w.z;
          acc[r][3] += xv * w.w;
        }
      }
    }
    #pragma unroll
    for (int r = 0; r < 4; ++r) {
      int row = row0 + ty + 8 * r;
      if (row < n) {
        float s = dinv[row];
        unsigned h0 = f2bf(s * acc[r][0]);
        unsigned h1 = f2bf(s * acc[r][1]);
        unsigned h2 = f2bf(s * acc[r][2]);
        unsigned h3 = f2bf(s * acc[r][3]);
        ((uint2*)(H + (size_t)row * D))[tx] = make_uint2(h0 | (h1 << 16), h2 | (h3 << 16));
      }
    }
  }
}

// ---------------- legacy kernels (fallback path only) ----------------

__global__ __launch_bounds__(256) void count_legacy_kernel(const int* __restrict__ dst, int E,
                                                           int* __restrict__ deg) {
  int e = blockIdx.x * 256 + threadIdx.x;
  if (e < E) atomicAdd(&deg[dst[e]], 1);
}

__global__ __launch_bounds__(256) void fused_fill_gemm_kernel(
    const int* __restrict__ src, const int* __restrict__ dst,
    int* __restrict__ ptr, int* __restrict__ csr, int E,
    const float* __restrict__ X, const float* __restrict__ W,
    const float* __restrict__ dinv, unsigned short* __restrict__ H, int n) {
  __shared__ float Ws[64 * WS_PAD];
  __shared__ float Xs[32 * 128];
  int sub = blockIdx.x & 7;
  if (sub < 2) {
    int fb = (blockIdx.x >> 3) * 2 + sub;
    int stride = 512 * 256;
    for (int e = fb * 256 + threadIdx.x; e < E; e += stride) {
      int d = dst[e];
      int pos = atomicAdd(&ptr[d], 1);
      csr[pos] = src[e];
    }
  } else {
    int gb = (blockIdx.x >> 3) * 6 + (sub - 2);
    gemm_body(X, W, dinv, H, n, gb, 1536, Ws, Xs);
  }
}

__global__ __launch_bounds__(256) void gemm128_kernel(const float* __restrict__ X,
                                                      const float* __restrict__ W,
                                                      const float* __restrict__ dinv,
                                                      unsigned short* __restrict__ H, int n) {
  __shared__ float Ws[64 * WS_PAD];
  __shared__ float Xs[32 * 128];
  gemm_body(X, W, dinv, H, n, blockIdx.x, gridDim.x, Ws, Xs);
}

__device__ __forceinline__ void gather_row_legacy(const int* __restrict__ csr, int start, int end,
                                                  const unsigned* __restrict__ Hu,
                                                  int i, int lane, float& ax, float& ay) {
  unsigned v = Hu[(size_t)i * 64 + lane];
  ax = __uint_as_float(v << 16);
  ay = __uint_as_float(v & 0xFFFF0000u);
  for (int e = start; e < end; ++e) {
    unsigned w = Hu[(size_t)csr[e] * 64 + lane];
    ax += __uint_as_float(w << 16);
    ay += __uint_as_float(w & 0xFFFF0000u);
  }
}

__global__ __launch_bounds__(256, 8) void gather_kernel_old(const int* __restrict__ csr,
                                                            const int* __restrict__ rend,
                                                            const float* __restrict__ dinv,
                                                            const unsigned* __restrict__ Hu,
                                                            const float* __restrict__ bias,
                                                            const float* __restrict__ perturb,
                                                            float* __restrict__ out, int n) {
  int i = (blockIdx.x << 2) + (threadIdx.x >> 6);
  if (i >= n) return;
  int lane = threadIdx.x & 63;
  int start = (i == 0) ? 0 : rend[i - 1];
  float ax, ay;
  gather_row_legacy(csr, start, rend[i], Hu, i, lane, ax, ay);
  float di = dinv[i];
  float2 p = ((const float2*)(perturb + (size_t)i * D))[lane];
  float2 o;
  o.x = bias[2 * lane + 0] + p.x + di * ax;
  o.y = bias[2 * lane + 1] + p.y + di * ay;
  ((float2*)(out + (size_t)i * D))[lane] = o;
}

// ---------------- quad gather helpers: 4 rows per wave, uint4 (16B) lanes ----------------
// Lane group g = lane>>4 owns row i0+g; lane sub = lane&15 covers cols [8*sub, 8*sub+8).

// plain: rows pre-scaled by dinv[src] (used for A2 in gather2)
__device__ __forceinline__ void gather_quad(const int* __restrict__ csr, int start, int end,
                                            const uint4* __restrict__ Hu4, int i, int sub,
                                            float acc[8]) {
  uint4 v = Hu4[(size_t)i * 16 + sub];
  acc[0] = bflo(v.x); acc[1] = bfhi(v.x);
  acc[2] = bflo(v.y); acc[3] = bfhi(v.y);
  acc[4] = bflo(v.z); acc[5] = bfhi(v.z);
  acc[6] = bflo(v.w); acc[7] = bfhi(v.w);
  int e = start;
  while (__ballot(e < end)) {
    uint4 w0 = {0u, 0u, 0u, 0u}, w1 = {0u, 0u, 0u, 0u};
    if (e < end)     w0 = Hu4[(size_t)csr[e] * 16 + sub];
    if (e + 1 < end) w1 = Hu4[(size_t)csr[e + 1] * 16 + sub];
    acc[0] += bflo(w0.x); acc[1] += bfhi(w0.x);
    acc[2] += bflo(w0.y); acc[3] += bfhi(w0.y);
    acc[4] += bflo(w0.z); acc[5] += bfhi(w0.z);
    acc[6] += bflo(w0.w); acc[7] += bfhi(w0.w);
    acc[0] += bflo(w1.x); acc[1] += bfhi(w1.x);
    acc[2] += bflo(w1.y); acc[3] += bfhi(w1.y);
    acc[4] += bflo(w1.z); acc[5] += bfhi(w1.z);
    acc[6] += bflo(w1.w); acc[7] += bfhi(w1.w);
    e += 2;
  }
}

// weighted: rows are RAW (no dinv); multiply each by dinv[src] in fp32 during gather.
__device__ __forceinline__ void gather_quad_w(const int* __restrict__ csr, int start, int end,
                                              const uint4* __restrict__ Hu4,
                                              const float* __restrict__ dinv,
                                              int i, int sub, float acc[8]) {
  float ds = dinv[i];
  uint4 v = Hu4[(size_t)i * 16 + sub];
  acc[0] = ds * bflo(v.x); acc[1] = ds * bfhi(v.x);
  acc[2] = ds * bflo(v.y); acc[3] = ds * bfhi(v.y);
  acc[4] = ds * bflo(v.z); acc[5] = ds * bfhi(v.z);
  acc[6] = ds * bflo(v.w); acc[7] = ds * bfhi(v.w);
  int e = start;
  while (__ballot(e < end)) {
    uint4 w0 = {0u, 0u, 0u, 0u}, w1 = {0u, 0u, 0u, 0u};
    float d0 = 0.f, d1 = 0.f;
    if (e < end)     { int j = csr[e];     w0 = Hu4[(size_t)j * 16 + sub]; d0 = dinv[j]; }
    if (e + 1 < end) { int j = csr[e + 1]; w1 = Hu4[(size_t)j * 16 + sub]; d1 = dinv[j]; }
    acc[0] += d0 * bflo(w0.x); acc[1] += d0 * bfhi(w0.x);
    acc[2] += d0 * bflo(w0.y); acc[3] += d0 * bfhi(w0.y);
    acc[4] += d0 * bflo(w0.z); acc[5] += d0 * bfhi(w0.z);
    acc[6] += d0 * bflo(w0.w); acc[7] += d0 * bfhi(w0.w);
    acc[0] += d1 * bflo(w1.x); acc[1] += d1 * bfhi(w1.x);
    acc[2] += d1 * bflo(w1.y); acc[3] += d1 * bfhi(w1.y);
    acc[4] += d1 * bflo(w1.z); acc[5] += d1 * bfhi(w1.z);
    acc[6] += d1 * bflo(w1.w); acc[7] += d1 * bfhi(w1.w);
    e += 2;
  }
}

// ---------------- standalone gather (gather2): 16 rows/block, quad layout, A2 prescaled ----------------

__global__ __launch_bounds__(256, 8) void gather_kernel(const int* __restrict__ csr,
                                                        const int* __restrict__ rptr,
                                                        const float* __restrict__ dinv,
                                                        const unsigned* __restrict__ Hu,
                                                        const float* __restrict__ bias,
                                                        const float* __restrict__ perturb,
                                                        float* __restrict__ out, int n) {
  const int lane = threadIdx.x & 63;
  const int g = lane >> 4;
  const int sub = lane & 15;
  int i = (blockIdx.x << 4) + ((threadIdx.x >> 6) << 2) + g;
  bool valid = i < n;
  int ic = valid ? i : (n - 1);
  int start = rptr[ic];
  int end = valid ? rptr[ic + 1] : start;
  float acc[8];
  gather_quad(csr, start, end, (const uint4*)Hu, ic, sub, acc);
  if (valid) {
    float di = dinv[i];
    float4 b0 = *(const float4*)&bias[sub * 8];
    float4 b1 = *(const float4*)&bias[sub * 8 + 4];
    float4 p0 = *(const float4*)&perturb[(size_t)i * D + sub * 8];
    float4 p1 = *(const float4*)&perturb[(size_t)i * D + sub * 8 + 4];
    float4 o0, o1;
    o0.x = b0.x + p0.x + di * acc[0];
    o0.y = b0.y + p0.y + di * acc[1];
    o0.z = b0.z + p0.z + di * acc[2];
    o0.w = b0.w + p0.w + di * acc[3];
    o1.x = b1.x + p1.x + di * acc[4];
    o1.y = b1.y + p1.y + di * acc[5];
    o1.z = b1.z + p1.z + di * acc[6];
    o1.w = b1.w + p1.w + di * acc[7];
    *(float4*)&out[(size_t)i * D + sub * 8] = o0;
    *(float4*)&out[(size_t)i * D + sub * 8 + 4] = o1;
  }
}

// ---------------- fused gather1 (dinv-weighted) + GEMM2 (MFMA bf16) ----------------

#define GG_PITCH 136

__global__ __launch_bounds__(512, 8) void gather_gemm_kernel(
    const int* __restrict__ csr, const int* __restrict__ rptr,
    const float* __restrict__ dinv, const unsigned* __restrict__ Hu,
    const float* __restrict__ bias, const float* __restrict__ perturb,
    const unsigned short* __restrict__ W2bf, unsigned short* __restrict__ H2, int n) {
  __shared__ unsigned short Ts[32 * GG_PITCH];  // 8.5 KB
  const int tid = threadIdx.x;
  const int wv = tid >> 6;
  const int lane = tid & 63;
  const int base = blockIdx.x << 5;  // 32 nodes per block

  // phase 1: weighted quad gather over RAW A1 — wave wv covers rows [wv*4, wv*4+4)
  {
    const int g = lane >> 4;
    const int sub = lane & 15;
    int row_in_block = (wv << 2) + g;
    int i = base + row_in_block;
    bool valid = i < n;
    int ic = valid ? i : (n - 1);
    int start = rptr[ic];
    int end = valid ? rptr[ic + 1] : start;
    float acc[8];
    gather_quad_w(csr, start, end, (const uint4*)Hu, dinv, ic, sub, acc);
    if (valid) {
      float di = dinv[i];
      float4 b0 = *(const float4*)&bias[sub * 8];
      float4 b1 = *(const float4*)&bias[sub * 8 + 4];
      float4 p0 = *(const float4*)&perturb[(size_t)i * D + sub * 8];
      float4 p1 = *(const float4*)&perturb[(size_t)i * D + sub * 8 + 4];
      unsigned q0 = (unsigned)f2bf(b0.x + p0.x + di * acc[0]) |
                    ((unsigned)f2bf(b0.y + p0.y + di * acc[1]) << 16);
      unsigned q1 = (unsigned)f2bf(b0.z + p0.z + di * acc[2]) |
                    ((unsigned)f2bf(b0.w + p0.w + di * acc[3]) << 16);
      unsigned q2 = (unsigned)f2bf(b1.x + p1.x + di * acc[4]) |
                    ((unsigned)f2bf(b1.y + p1.y + di * acc[5]) << 16);
      unsigned q3 = (unsigned)f2bf(b1.z + p1.z + di * acc[6]) |
                    ((unsigned)f2bf(b1.w + p1.w + di * acc[7]) << 16);
      uint4 pack = make_uint4(q0, q1, q2, q3);
      *(uint4*)&Ts[row_in_block * GG_PITCH + sub * 8] = pack;
    }
  }
  __syncthreads();

  // phase 2: R[32][128] = Ts @ W2bf^T ; wave wv: m-tile = wv>>2, n-tiles {wv&3, (wv&3)+4}
  const int mt = wv >> 2;
  const int nt0 = wv & 3;
  const int m = lane & 15;
  const int quad = lane >> 4;  // 0..3
  const unsigned short* Wrow0 = W2bf + (size_t)(nt0 * 16 + m) * 128;
  const unsigned short* Wrow1 = W2bf + (size_t)((nt0 + 4) * 16 + m) * 128;
  f32x4 acc0 = {0.f, 0.f, 0.f, 0.f};
  f32x4 acc1 = {0.f, 0.f, 0.f, 0.f};
  #pragma unroll
  for (int s = 0; s < 4; ++s) {
    int k = (s << 5) + (quad << 3);
    bf16x8 a  = *(const bf16x8*)&Ts[(mt * 16 + m) * GG_PITCH + k];
    bf16x8 b0 = *(const bf16x8*)&Wrow0[k];
    bf16x8 b1 = *(const bf16x8*)&Wrow1[k];
    acc0 = __builtin_amdgcn_mfma_f32_16x16x32_bf16(a, b0, acc0, 0, 0, 0);
    acc1 = __builtin_amdgcn_mfma_f32_16x16x32_bf16(a, b1, acc1, 0, 0, 0);
  }
  // C/D layout: col = lane&15, row = quad*4 + reg ; A2 stays prescaled by dinv
  #pragma unroll
  for (int r = 0; r < 4; ++r) {
    int row = mt * 16 + (quad << 2) + r;
    int gg = base + row;
    if (gg < n) {
      float s = dinv[gg];
      H2[(size_t)gg * D + nt0 * 16 + m]       = f2bf(s * acc0[r]);
      H2[(size_t)gg * D + (nt0 + 4) * 16 + m] = f2bf(s * acc1[r]);
    }
  }
}

// ---------------- launch ----------------

extern "C" void kernel_launch(void* const* d_in, const int* in_sizes, int n_in,
                              void* d_out, int out_size, void* d_ws, size_t ws_size,
                              hipStream_t stream) {
  const float* x  = (const float*)d_in[0];
  const int*   ei = (const int*)d_in[1];
  const float* pf = (const float*)d_in[2];
  const float* pl = (const float*)d_in[3];
  const float* W1 = (const float*)d_in[4];
  const float* b1 = (const float*)d_in[5];
  const float* W2 = (const float*)d_in[6];
  const float* b2 = (const float*)d_in[7];
  float* out = (float*)d_out;

  const int n = in_sizes[0] / D;
  const int E = in_sizes[1] / 2;
  const int* src = ei;      // edge_index[0]
  const int* dst = ei + E;  // edge_index[1]

  // workspace layout
  int*   deg       = (int*)d_ws;                     // [n]
  float* dinv      = (float*)d_ws + n;               // [n]
  int*   ptr       = (int*)d_ws + 2 * n;             // [n+1] (start offsets; immutable in fused path)
  int*   blockSums = (int*)d_ws + 3 * n + 1;         // [<=512]
  int*   csr       = (int*)d_ws + 3 * n + 1 + 512;   // [E]
  size_t a1_off = ((size_t)(3 * n + 1 + 512 + E) * 4 + 255) & ~(size_t)255;
  unsigned short* A1 = (unsigned short*)((char*)d_ws + a1_off);
  unsigned short* A2 = A1 + (size_t)n * D;
  unsigned short* W2bf = A2 + (size_t)n * D;     // [128*128] bf16, 32 KB
  unsigned short* W1h  = W2bf + 128 * 128;       // [128*128] bf16, 32 KB
  unsigned short* W1l  = W1h + 128 * 128;        // [128*128] bf16, 32 KB
  int* rank = (int*)A2;                          // [E] aliases A2 (dead until gather_gemm)
  size_t needed = a1_off + (2 * (size_t)n * D + 3 * 128 * 128) * sizeof(unsigned short);
  const bool fused_l2 = (ws_size >= needed);  // constant across calls -> capture-safe

  const int nb_n = (n + 255) / 256;
  const int nb_e = (E + 255) / 256;
  const int nb_g16 = (n + 15) / 16;
  const int nb_g4 = (n + 3) / 4;

  hipMemsetAsync(deg, 0, (size_t)n * sizeof(int), stream);

  if (fused_l2) {
    // W tables first (tiny); then count+rank || GEMM1_raw fully overlapped (5:3 split)
    wprep_kernel<<<16, 256, 0, stream>>>(W2, W2bf, W1, W1h, W1l);
    count_gemm1_kernel<<<FUSED_GRID, 256, 0, stream>>>(dst, E, deg, rank, x, W1h, W1l, A1, n);
    scan_blocksum_kernel<<<nb_n, 256, 0, stream>>>(deg, n, blockSums);
    scan_top_kernel<<<1, 512, 0, stream>>>(blockSums, nb_n);
    scan_write_kernel<<<nb_n, 256, 0, stream>>>(deg, n, blockSums, ptr, dinv);
    // atomic-free fill (standalone, ~bandwidth-bound)
    fill_kernel<<<FUSED_GRID, 256, 0, stream>>>(src, dst, ptr, rank, csr, E);
    // gather1 (dinv-weighted over raw A1) + GEMM2 -> A2 ; gather2 -> out
    gather_gemm_kernel<<<(n + 31) / 32, 512, 0, stream>>>(csr, ptr, dinv, (const unsigned*)A1,
                                                          b1, pf, W2bf, A2, n);
    gather_kernel<<<nb_g16, 256, 0, stream>>>(csr, ptr, dinv, (const unsigned*)A2, b2, pl, out, n);
  } else {
    // fallback: fp32 VALU gemm, atomic fill (ptr becomes row_end), legacy gathers
    count_legacy_kernel<<<nb_e, 256, 0, stream>>>(dst, E, deg);
    scan_blocksum_kernel<<<nb_n, 256, 0, stream>>>(deg, n, blockSums);
    scan_top_kernel<<<1, 512, 0, stream>>>(blockSums, nb_n);
    scan_write_kernel<<<nb_n, 256, 0, stream>>>(deg, n, blockSums, ptr, dinv);
    fused_fill_gemm_kernel<<<FUSED_GRID, 256, 0, stream>>>(src, dst, ptr, csr, E, x, W1, dinv, A1, n);
    gather_kernel_old<<<nb_g4, 256, 0, stream>>>(csr, ptr, dinv, (const unsigned*)A1, b1, pf, out, n);
    gemm128_kernel<<<1024, 256, 0, stream>>>(out, W2, dinv, A1, n);
    gather_kernel_old<<<nb_g4, 256, 0, stream>>>(csr, ptr, dinv, (const unsigned*)A1, b2, pl, out, n);
  }
}